// Round 6
// baseline (828.609 us; speedup 1.0000x reference)
//
#include <hip/hip_runtime.h>
#include <hip/hip_bf16.h>
#include <math.h>

// ---------------------------------------------------------------------------
// B=32, N=128, D=5000, H=256, C=4
//   1) x_tilde = x @ Er^T  — MFMA bf16 NT gemm, K-SPLIT z=4 (R12), partials
//      into P's free space, reduce4_k sums into xt.
//   2) P = xt @ [W...]^T — gemm_mfma_w6 reads the 6 W matrices DIRECTLY
//      (bn>>2 selects matrix, (bn&3)*64+row the row) — no Wcat memcpys (R13).
//   3) UTb = bf16-packed transposed U
//   4) build_schedule: level schedule + TPB-group table + flags + ticket=0
//   5) tree_scan_df (R13): dataflow sync with DYNAMIC TICKET dispatch —
//      WGs atomicAdd a global ticket for the next group instead of static
//      striding. R5 counters: scan 447us = 2.5x the ~180us critical path;
//      residual was head-of-line blocking of the static assignment. Greedy
//      list scheduling bounds makespan by CP + work/P ~ 240us. Deadlock-free:
//      tickets issue in schedule order; the minimal in-flight group always
//      has all parents complete. TPB=2 body unchanged (proven).
//   6) epilogue
// ---------------------------------------------------------------------------

#define H_DIM 256
#define N_NODES 128
#define B_TREES 32
#define MAXL 128
#define TPB 2
#define GRID_WGS 256

typedef short bf16x8 __attribute__((ext_vector_type(8)));
typedef float f32x4 __attribute__((ext_vector_type(4)));

__device__ __forceinline__ float sigmoidf_(float x) {
    return 1.0f / (1.0f + expf(-x));
}
__device__ __forceinline__ unsigned bfp(float x) {  // fp32 -> bf16 bits (RNE)
    unsigned u = __float_as_uint(x);
    return (u + 0x7fffu + ((u >> 16) & 1u)) >> 16;
}
__device__ __forceinline__ float bflo(unsigned w) { return __uint_as_float(w << 16); }
__device__ __forceinline__ float bfhi(unsigned w) { return __uint_as_float(w & 0xffff0000u); }

__device__ __forceinline__ void unpack8(uint4 v, float* f) {
    f[0] = bflo(v.x); f[1] = bfhi(v.x);
    f[2] = bflo(v.y); f[3] = bfhi(v.y);
    f[4] = bflo(v.z); f[5] = bfhi(v.z);
    f[6] = bflo(v.w); f[7] = bfhi(v.w);
}

// Coherent (device-scope, relaxed) accessors.
__device__ __forceinline__ float coh_load(const float* p) {
    return __hip_atomic_load(p, __ATOMIC_RELAXED, __HIP_MEMORY_SCOPE_AGENT);
}
__device__ __forceinline__ void coh_store(float* p, float v) {
    __hip_atomic_store(p, v, __ATOMIC_RELAXED, __HIP_MEMORY_SCOPE_AGENT);
}
__device__ __forceinline__ unsigned coh_loadu(const unsigned* p) {
    return __hip_atomic_load(p, __ATOMIC_RELAXED, __HIP_MEMORY_SCOPE_AGENT);
}
__device__ __forceinline__ void coh_storeu(unsigned* p, unsigned v) {
    __hip_atomic_store(p, v, __ATOMIC_RELAXED, __HIP_MEMORY_SCOPE_AGENT);
}

// ---------------------------------------------------------------------------
// MFMA bf16 NT GEMM with K-chunking (gemm1): C = A[M,Kchunk] @ B[N,Kchunk]^T.
// Verified fragment maps (learn_hip m89/m120).
// ---------------------------------------------------------------------------
__global__ __launch_bounds__(256) void gemm_mfma_nt(
    const float* __restrict__ A, const float* __restrict__ B,
    float* __restrict__ C, int K, int ldc, int Kc, int zStride) {
    __shared__ short As[64][40];
    __shared__ short Bs[64][40];
    const int tid = threadIdx.x;
    const int bm = blockIdx.x, bn = blockIdx.y;
    const int z = blockIdx.z;
    const int k_begin = z * Kc;
    const int k_end = (k_begin + Kc < K) ? (k_begin + Kc) : K;
    float* Cz = C + (size_t)z * zStride;
    const int row = tid >> 2;
    const int quad = tid & 3;
    const int wave = tid >> 6;
    const int lane = tid & 63;
    const int lm = lane & 15;
    const int kq = lane >> 4;

    f32x4 acc[4];
#pragma unroll
    for (int i = 0; i < 4; ++i) acc[i] = (f32x4){0.f, 0.f, 0.f, 0.f};

    for (int k0 = k_begin; k0 < k_end; k0 += 32) {
        const int kbase = k0 + quad * 8;
        {
            float a8[8];
            const float* Ap = A + (size_t)(bm * 64 + row) * K + kbase;
            if (kbase + 8 <= k_end) {
                const float4 v0 = *(const float4*)Ap;
                const float4 v1 = *(const float4*)(Ap + 4);
                a8[0] = v0.x; a8[1] = v0.y; a8[2] = v0.z; a8[3] = v0.w;
                a8[4] = v1.x; a8[5] = v1.y; a8[6] = v1.z; a8[7] = v1.w;
            } else {
#pragma unroll
                for (int i = 0; i < 8; ++i)
                    a8[i] = (kbase + i < k_end) ? Ap[i] : 0.f;
            }
            uint4 v;
            v.x = bfp(a8[0]) | (bfp(a8[1]) << 16);
            v.y = bfp(a8[2]) | (bfp(a8[3]) << 16);
            v.z = bfp(a8[4]) | (bfp(a8[5]) << 16);
            v.w = bfp(a8[6]) | (bfp(a8[7]) << 16);
            *(uint4*)&As[row][quad * 8] = v;
        }
        {
            float b8[8];
            const float* Bp = B + (size_t)(bn * 64 + row) * K + kbase;
            if (kbase + 8 <= k_end) {
                const float4 v0 = *(const float4*)Bp;
                const float4 v1 = *(const float4*)(Bp + 4);
                b8[0] = v0.x; b8[1] = v0.y; b8[2] = v0.z; b8[3] = v0.w;
                b8[4] = v1.x; b8[5] = v1.y; b8[6] = v1.z; b8[7] = v1.w;
            } else {
#pragma unroll
                for (int i = 0; i < 8; ++i)
                    b8[i] = (kbase + i < k_end) ? Bp[i] : 0.f;
            }
            uint4 v;
            v.x = bfp(b8[0]) | (bfp(b8[1]) << 16);
            v.y = bfp(b8[2]) | (bfp(b8[3]) << 16);
            v.z = bfp(b8[4]) | (bfp(b8[5]) << 16);
            v.w = bfp(b8[6]) | (bfp(b8[7]) << 16);
            *(uint4*)&Bs[row][quad * 8] = v;
        }
        __syncthreads();
        const bf16x8 af = *(const bf16x8*)&As[wave * 16 + lm][kq * 8];
#pragma unroll
        for (int nt = 0; nt < 4; ++nt) {
            const bf16x8 bf = *(const bf16x8*)&Bs[nt * 16 + lm][kq * 8];
            acc[nt] = __builtin_amdgcn_mfma_f32_16x16x32_bf16(af, bf, acc[nt], 0, 0, 0);
        }
        __syncthreads();
    }
#pragma unroll
    for (int nt = 0; nt < 4; ++nt) {
#pragma unroll
        for (int r = 0; r < 4; ++r) {
            const int gm = bm * 64 + wave * 16 + kq * 4 + r;
            const int gn = bn * 64 + nt * 16 + lm;
            Cz[(size_t)gm * ldc + gn] = acc[nt][r];
        }
    }
}

// gemm2: P[4096,1536] = xt[4096,256] @ Wcat^T where Wcat rows come directly
// from 6 separate W[256,256] matrices (no concat). K=256 fixed, full tiles.
__global__ __launch_bounds__(256) void gemm_mfma_w6(
    const float* __restrict__ A,
    const float* __restrict__ B0, const float* __restrict__ B1,
    const float* __restrict__ B2, const float* __restrict__ B3,
    const float* __restrict__ B4, const float* __restrict__ B5,
    float* __restrict__ C, int ldc) {
    __shared__ short As[64][40];
    __shared__ short Bs[64][40];
    const int tid = threadIdx.x;
    const int bm = blockIdx.x, bn = blockIdx.y;
    const float* Bsel[6] = {B0, B1, B2, B3, B4, B5};
    const int row = tid >> 2;
    const int quad = tid & 3;
    const int wave = tid >> 6;
    const int lane = tid & 63;
    const int lm = lane & 15;
    const int kq = lane >> 4;
    const float* Brow = Bsel[bn >> 2] + (size_t)((bn & 3) * 64 + row) * 256;
    const float* Arow = A + (size_t)(bm * 64 + row) * 256;

    f32x4 acc[4];
#pragma unroll
    for (int i = 0; i < 4; ++i) acc[i] = (f32x4){0.f, 0.f, 0.f, 0.f};

#pragma unroll
    for (int kt = 0; kt < 8; ++kt) {
        const int kbase = kt * 32 + quad * 8;
        {
            const float4 v0 = *(const float4*)(Arow + kbase);
            const float4 v1 = *(const float4*)(Arow + kbase + 4);
            uint4 v;
            v.x = bfp(v0.x) | (bfp(v0.y) << 16);
            v.y = bfp(v0.z) | (bfp(v0.w) << 16);
            v.z = bfp(v1.x) | (bfp(v1.y) << 16);
            v.w = bfp(v1.z) | (bfp(v1.w) << 16);
            *(uint4*)&As[row][quad * 8] = v;
        }
        {
            const float4 v0 = *(const float4*)(Brow + kbase);
            const float4 v1 = *(const float4*)(Brow + kbase + 4);
            uint4 v;
            v.x = bfp(v0.x) | (bfp(v0.y) << 16);
            v.y = bfp(v0.z) | (bfp(v0.w) << 16);
            v.z = bfp(v1.x) | (bfp(v1.y) << 16);
            v.w = bfp(v1.z) | (bfp(v1.w) << 16);
            *(uint4*)&Bs[row][quad * 8] = v;
        }
        __syncthreads();
        const bf16x8 af = *(const bf16x8*)&As[wave * 16 + lm][kq * 8];
#pragma unroll
        for (int nt = 0; nt < 4; ++nt) {
            const bf16x8 bf = *(const bf16x8*)&Bs[nt * 16 + lm][kq * 8];
            acc[nt] = __builtin_amdgcn_mfma_f32_16x16x32_bf16(af, bf, acc[nt], 0, 0, 0);
        }
        __syncthreads();
    }
#pragma unroll
    for (int nt = 0; nt < 4; ++nt) {
#pragma unroll
        for (int r = 0; r < 4; ++r) {
            const int gm = bm * 64 + wave * 16 + kq * 4 + r;
            const int gn = bn * 64 + nt * 16 + lm;
            C[(size_t)gm * ldc + gn] = acc[nt][r];
        }
    }
}

// xt = sum of 4 K-chunk partials (each 4096*256 f32, stored in P's space)
__global__ __launch_bounds__(256) void reduce4_k(
    const float* __restrict__ Pp, float* __restrict__ xt) {
    const int i = (blockIdx.x * 256 + threadIdx.x) * 4;
    const float4 a = *(const float4*)(Pp + i);
    const float4 b = *(const float4*)(Pp + 1048576 + i);
    const float4 c = *(const float4*)(Pp + 2097152 + i);
    const float4 d = *(const float4*)(Pp + 3145728 + i);
    float4 s;
    s.x = a.x + b.x + c.x + d.x;
    s.y = a.y + b.y + c.y + d.y;
    s.z = a.z + b.z + c.z + d.z;
    s.w = a.w + b.w + c.w + d.w;
    *(float4*)(xt + i) = s;
}

// UTb[(m*32 + jblk)*256 + h] = uint4 of 8 bf16 = U_m[h][8*jblk .. 8*jblk+7]
__global__ __launch_bounds__(256) void transpose_pack_u(
    const float* __restrict__ U0, const float* __restrict__ U1,
    const float* __restrict__ U2, const float* __restrict__ U3,
    const float* __restrict__ U4, const float* __restrict__ U5,
    const float* __restrict__ U6, const float* __restrict__ U7,
    const float* __restrict__ U8, uint4* __restrict__ UTb) {
    const float* Us[9] = {U0, U1, U2, U3, U4, U5, U6, U7, U8};
    const int jb = blockIdx.x;
    const int m = blockIdx.y;
    const int h = threadIdx.x;
    const float* U = Us[m] + (size_t)h * 256 + jb * 8;
    uint4 v;
    v.x = bfp(U[0]) | (bfp(U[1]) << 16);
    v.y = bfp(U[2]) | (bfp(U[3]) << 16);
    v.z = bfp(U[4]) | (bfp(U[5]) << 16);
    v.w = bfp(U[6]) | (bfp(U[7]) << 16);
    UTb[(size_t)(m * 32 + jb) * 256 + h] = v;
}

// Level schedule + TPB-group table + zeroed flags + zeroed ticket.
__global__ __launch_bounds__(256) void build_schedule(
    const int* __restrict__ parents, int* __restrict__ sched,
    int* __restrict__ level_off, int* __restrict__ gstart,
    int* __restrict__ gend, int* __restrict__ ngrp,
    unsigned* __restrict__ ready, unsigned* __restrict__ ticket) {
    __shared__ unsigned char depth[B_TREES][N_NODES];
    __shared__ int counts[MAXL];
    __shared__ int base[MAXL + 1];
    const int tid = threadIdx.x;
    if (tid == 0) coh_storeu(ticket, 0u);
    for (int k = tid; k < B_TREES * N_NODES; k += 256)
        coh_storeu(&ready[k], 0u);
    for (int k = tid; k < MAXL; k += 256) counts[k] = 0;
    __syncthreads();
    if (tid < B_TREES) {
        depth[tid][0] = 0;
        for (int i = 1; i < N_NODES; ++i) {
            const int p = parents[tid * N_NODES + i];
            depth[tid][i] = (unsigned char)(depth[tid][p - 1] + 1);
        }
    }
    __syncthreads();
    for (int k = tid; k < B_TREES * N_NODES; k += 256)
        atomicAdd(&counts[depth[k >> 7][k & 127]], 1);
    __syncthreads();
    if (tid == 0) {
        int acc = 0;
        int nl = 0;
        for (int l = 0; l < MAXL; ++l) {
            base[l] = acc;
            acc += counts[l];
            if (counts[l] > 0) nl = l + 1;
        }
        base[MAXL] = acc;
        level_off[MAXL + 1] = nl;
        int ng = 0;
        for (int l = 0; l < nl; ++l) {
            for (int s = base[l]; s < base[l + 1]; s += TPB) {
                gstart[ng] = s;
                gend[ng] = (s + TPB < base[l + 1]) ? s + TPB : base[l + 1];
                ++ng;
            }
        }
        *ngrp = ng;
    }
    __syncthreads();
    for (int k = tid; k <= MAXL; k += 256) level_off[k] = base[k];
    for (int k = tid; k < MAXL; k += 256) counts[k] = 0;
    __syncthreads();
    for (int k = tid; k < B_TREES * N_NODES; k += 256) {
        const int d = depth[k >> 7][k & 127];
        const int pos = base[d] + atomicAdd(&counts[d], 1);
        sched[pos] = k;
    }
}

// Dataflow tree GRU — TPB=2 body, ready-flag sync, DYNAMIC ticket dispatch.
__global__ __launch_bounds__(256, 1) void tree_scan_df(
    const float* __restrict__ P, const uint4* __restrict__ UTb,
    const int* __restrict__ parents,
    const int* __restrict__ sched,
    const int* __restrict__ gstart, const int* __restrict__ gend,
    const int* __restrict__ ngrp, unsigned* __restrict__ ready,
    unsigned* __restrict__ ticket,
    float* __restrict__ Ssh, float* __restrict__ Sru) {
    const int h = threadIdx.x;
    __shared__ float hsp_s[H_DIM][TPB];
    __shared__ float hrp_s[H_DIM][TPB];
    __shared__ float aux_s[H_DIM][TPB];
    __shared__ float hsh_s[H_DIM][TPB];
    __shared__ int g_sh;

    const uint4* __restrict__ U0b = UTb + 0 * 8192;
    const uint4* __restrict__ U1b = UTb + 1 * 8192;
    const uint4* __restrict__ U2b = UTb + 2 * 8192;
    const uint4* __restrict__ U3b = UTb + 3 * 8192;
    const uint4* __restrict__ U4b = UTb + 4 * 8192;
    const uint4* __restrict__ U5b = UTb + 5 * 8192;
    const uint4* __restrict__ U6b = UTb + 6 * 8192;
    const uint4* __restrict__ U7b = UTb + 7 * 8192;
    const uint4* __restrict__ U8b = UTb + 8 * 8192;

    const int ng = ngrp[0];
    for (;;) {
        if (h == 0) g_sh = (int)atomicAdd(ticket, 1u);
        __syncthreads();
        const int g = g_sh;
        if (g >= ng) break;
        const int s = gstart[g];
        const int e = gend[g];
        // ---- wait for parents (parallel read-only coherent polls) ----
        if (h < e - s) {
            const int nd = sched[s + h];
            const int p = parents[nd];
            if (p != 0) {
                const unsigned* f = &ready[(nd & ~127) + p - 1];
                while (coh_loadu(f) == 0u) __builtin_amdgcn_s_sleep(1);
            }
        }
        __syncthreads();

        int  node[TPB];
        bool val[TPB];
        float phs[TPB], phr[TPB];
#pragma unroll
        for (int t = 0; t < TPB; ++t) {
            const int idx = s + t;
            val[t] = idx < e;
            const int nd = val[t] ? sched[idx] : sched[s];
            node[t] = nd;
            const int p = parents[nd];
            float hs = 0.f, hr = 0.f;
            if (p != 0) {
                const size_t pr = ((size_t)((nd & ~127) + p - 1)) * H_DIM + h;
                hs = coh_load(&Ssh[pr]);
                hr = coh_load(&Sru[pr]);
            }
            phs[t] = hs;
            phr[t] = hr;
        }
        *(float2*)&hsp_s[h][0] = make_float2(phs[0], phs[1]);
        *(float2*)&hrp_s[h][0] = make_float2(phr[0], phr[1]);
        __syncthreads();

        // ---------------- stage 1: r_sh, z_sh ----------------
        float pr_[TPB], pz_[TPB];
#pragma unroll
        for (int t = 0; t < TPB; ++t) {
            const float* Pi = P + (size_t)node[t] * 1536;
            pr_[t] = Pi[h];
            pz_[t] = Pi[256 + h];
        }
        float dr[TPB] = {0.f, 0.f};
        float dz[TPB] = {0.f, 0.f};
#pragma unroll 4
        for (int jb = 0; jb < 32; ++jb) {
            const uint4 w0 = U0b[jb * 256 + h];
            const uint4 w1 = U1b[jb * 256 + h];
            float a[8], c[8];
            unpack8(w0, a);
            unpack8(w1, c);
#pragma unroll
            for (int q = 0; q < 8; ++q) {
                const float2 hv = *(const float2*)&hsp_s[jb * 8 + q][0];
                dr[0] = fmaf(a[q], hv.x, dr[0]);
                dr[1] = fmaf(a[q], hv.y, dr[1]);
                dz[0] = fmaf(c[q], hv.x, dz[0]);
                dz[1] = fmaf(c[q], hv.y, dz[1]);
            }
        }
        float z_sh[TPB], vsh[TPB];
#pragma unroll
        for (int t = 0; t < TPB; ++t) {
            const float r_sh = sigmoidf_(pr_[t] + dr[t]);
            z_sh[t] = sigmoidf_(pz_[t] + dz[t]);
            vsh[t] = phs[t] * r_sh;
        }
        *(float2*)&aux_s[h][0] = make_float2(vsh[0], vsh[1]);
        __syncthreads();

        // ---------------- stage 2: h_sh ----------------
        float ph_[TPB];
#pragma unroll
        for (int t = 0; t < TPB; ++t)
            ph_[t] = P[(size_t)node[t] * 1536 + 512 + h];
        float dh[TPB] = {0.f, 0.f};
#pragma unroll 8
        for (int jb = 0; jb < 32; ++jb) {
            const uint4 w2 = U2b[jb * 256 + h];
            float a[8];
            unpack8(w2, a);
#pragma unroll
            for (int q = 0; q < 8; ++q) {
                const float2 hv = *(const float2*)&aux_s[jb * 8 + q][0];
                dh[0] = fmaf(a[q], hv.x, dh[0]);
                dh[1] = fmaf(a[q], hv.y, dh[1]);
            }
        }
        float hsh[TPB];
#pragma unroll
        for (int t = 0; t < TPB; ++t) {
            const float hsh_t = tanhf(ph_[t] + dh[t]);
            hsh[t] = (1.f - z_sh[t]) * phs[t] + z_sh[t] * hsh_t;
            if (val[t])
                coh_store(&Ssh[(size_t)node[t] * H_DIM + h], hsh[t]);
        }
        *(float2*)&hsh_s[h][0] = make_float2(hsh[0], hsh[1]);
        __syncthreads();

        // ---------------- stage 3: r_ru, z_ru ----------------
        float pru_[TPB], pzu_[TPB];
#pragma unroll
        for (int t = 0; t < TPB; ++t) {
            const float* Pi = P + (size_t)node[t] * 1536;
            pru_[t] = Pi[768 + h];
            pzu_[t] = Pi[1024 + h];
        }
        float er[TPB] = {0.f, 0.f};
        float ez[TPB] = {0.f, 0.f};
        float fr[TPB] = {0.f, 0.f};
        float fz[TPB] = {0.f, 0.f};
#pragma unroll 2
        for (int jb = 0; jb < 32; ++jb) {
            const uint4 w3 = U3b[jb * 256 + h];
            const uint4 w4 = U4b[jb * 256 + h];
            const uint4 w6 = U6b[jb * 256 + h];
            const uint4 w7 = U7b[jb * 256 + h];
            float a3[8], a4[8], a6[8], a7[8];
            unpack8(w3, a3);
            unpack8(w4, a4);
            unpack8(w6, a6);
            unpack8(w7, a7);
#pragma unroll
            for (int q = 0; q < 8; ++q) {
                const float2 hr2 = *(const float2*)&hrp_s[jb * 8 + q][0];
                const float2 hs2 = *(const float2*)&hsh_s[jb * 8 + q][0];
                er[0] = fmaf(a3[q], hr2.x, er[0]);
                er[1] = fmaf(a3[q], hr2.y, er[1]);
                ez[0] = fmaf(a4[q], hr2.x, ez[0]);
                ez[1] = fmaf(a4[q], hr2.y, ez[1]);
                fr[0] = fmaf(a6[q], hs2.x, fr[0]);
                fr[1] = fmaf(a6[q], hs2.y, fr[1]);
                fz[0] = fmaf(a7[q], hs2.x, fz[0]);
                fz[1] = fmaf(a7[q], hs2.y, fz[1]);
            }
        }
        float z_ru[TPB], v2[TPB];
#pragma unroll
        for (int t = 0; t < TPB; ++t) {
            const float r_ru = sigmoidf_(pru_[t] + er[t] + fr[t]);
            z_ru[t] = sigmoidf_(pzu_[t] + ez[t] + fz[t]);
            v2[t] = phr[t] * r_ru;
        }
        *(float2*)&aux_s[h][0] = make_float2(v2[0], v2[1]);
        __syncthreads();

        // ---------------- stage 4: h_ru ----------------
        float phu_[TPB];
#pragma unroll
        for (int t = 0; t < TPB; ++t)
            phu_[t] = P[(size_t)node[t] * 1536 + 1280 + h];
        float eh[TPB] = {0.f, 0.f};
        float fh[TPB] = {0.f, 0.f};
#pragma unroll 4
        for (int jb = 0; jb < 32; ++jb) {
            const uint4 w5 = U5b[jb * 256 + h];
            const uint4 w8 = U8b[jb * 256 + h];
            float a5[8], a8[8];
            unpack8(w5, a5);
            unpack8(w8, a8);
#pragma unroll
            for (int q = 0; q < 8; ++q) {
                const float2 v4 = *(const float2*)&aux_s[jb * 8 + q][0];
                const float2 s4 = *(const float2*)&hsh_s[jb * 8 + q][0];
                eh[0] = fmaf(a5[q], v4.x, eh[0]);
                eh[1] = fmaf(a5[q], v4.y, eh[1]);
                fh[0] = fmaf(a8[q], s4.x, fh[0]);
                fh[1] = fmaf(a8[q], s4.y, fh[1]);
            }
        }
#pragma unroll
        for (int t = 0; t < TPB; ++t) {
            const float hru_t = tanhf(phu_[t] + eh[t] + fh[t]);
            const float h_ru = (1.f - z_ru[t]) * phr[t] + z_ru[t] * hru_t;
            if (val[t])
                coh_store(&Sru[(size_t)node[t] * H_DIM + h], h_ru);
        }
        // drain ALL waves' coherent state stores, THEN publish flags.
        __syncthreads();
        if (h < e - s)
            coh_storeu(&ready[sched[s + h]], 1u);
        __syncthreads();
    }
}

__global__ __launch_bounds__(256) void epilogue_k(
    const float* __restrict__ Sru, const int* __restrict__ is_leaf,
    const float* __restrict__ Vr, const float* __restrict__ br,
    float* __restrict__ out) {
    const int b = blockIdx.x;
    const int h = threadIdx.x;
    float m = -3.402823466e38f;
    for (int n = 0; n < N_NODES; ++n) {
        const float v = Sru[((size_t)b * N_NODES + n) * H_DIM + h];
        if (is_leaf[b * N_NODES + n] != 0) m = fmaxf(m, v);
    }
    __shared__ float hm[H_DIM];
    __shared__ float lg[4];
    hm[h] = m;
    __syncthreads();
    if (h < 4) {
        float acc = br[h];
#pragma unroll 8
        for (int j = 0; j < H_DIM; ++j) acc = fmaf(Vr[h * 256 + j], hm[j], acc);
        lg[h] = acc;
    }
    __syncthreads();
    if (h == 0) {
        const float mx = fmaxf(fmaxf(lg[0], lg[1]), fmaxf(lg[2], lg[3]));
        const float e0 = expf(lg[0] - mx);
        const float e1 = expf(lg[1] - mx);
        const float e2 = expf(lg[2] - mx);
        const float e3 = expf(lg[3] - mx);
        const float s = e0 + e1 + e2 + e3;
        out[b * 4 + 0] = e0 / s;
        out[b * 4 + 1] = e1 / s;
        out[b * 4 + 2] = e2 / s;
        out[b * 4 + 3] = e3 / s;
    }
}

extern "C" void kernel_launch(void* const* d_in, const int* in_sizes, int n_in,
                              void* d_out, int out_size, void* d_ws, size_t ws_size,
                              hipStream_t stream) {
    const float* x      = (const float*)d_in[0];
    const float* Er     = (const float*)d_in[1];
    const float* Wsr_r  = (const float*)d_in[2];
    const float* Usr_r  = (const float*)d_in[3];
    const float* Wsr_z  = (const float*)d_in[4];
    const float* Usr_z  = (const float*)d_in[5];
    const float* Wsr_h  = (const float*)d_in[6];
    const float* Usr_h  = (const float*)d_in[7];
    const float* Wr_r   = (const float*)d_in[8];
    const float* Ur_r   = (const float*)d_in[9];
    const float* Usr2r_r= (const float*)d_in[10];
    const float* Wr_z   = (const float*)d_in[11];
    const float* Ur_z   = (const float*)d_in[12];
    const float* Usr2r_z= (const float*)d_in[13];
    const float* Wr_h   = (const float*)d_in[14];
    const float* Ur_h   = (const float*)d_in[15];
    const float* Usr2r_h= (const float*)d_in[16];
    const float* Vr     = (const float*)d_in[17];
    const float* br     = (const float*)d_in[18];
    const int*   parents= (const int*)d_in[19];
    const int*   is_leaf= (const int*)d_in[20];
    float* out = (float*)d_out;

    float* ws = (float*)d_ws;
    float* xt   = ws;                          // 4096*256  f32
    float* P    = xt + 1048576;                // 4096*1536 f32 (also gemm1 partials)
    float* Wcat = P + 6291456;                 // (unused, kept for layout)
    uint4* UTb  = (uint4*)(Wcat + 393216);     // 9*32*256 uint4
    float* Ssh  = (float*)(UTb + 73728);       // 32*128*256 f32
    float* Sru  = Ssh + 1048576;               // 32*128*256 f32
    int*   sched     = (int*)(Sru + 1048576);  // 4096
    int*   level_off = sched + 4096;           // 192
    unsigned* ready  = (unsigned*)(level_off + 192);  // 4096
    int*   gstart    = (int*)(ready + 4096);   // 4096
    int*   gend      = gstart + 4096;          // 4096
    int*   ngrp      = gend + 4096;            // 16
    unsigned* ticket = (unsigned*)(ngrp + 16); // 16

    dim3 blk(256);

    // 1) x_tilde = x @ Er^T (M=4096, N=256, K=5000), K-split z=4.
    gemm_mfma_nt<<<dim3(64, 4, 4), blk, 0, stream>>>(x, Er, P, 5000, 256,
                                                     1280, 1048576);
    reduce4_k<<<dim3(1024), blk, 0, stream>>>(P, xt);

    // 2) P = xt @ [W...]^T (M=4096, N=1536, K=256), direct-W (no memcpys)
    gemm_mfma_w6<<<dim3(64, 24), blk, 0, stream>>>(
        xt, Wsr_r, Wsr_z, Wsr_h, Wr_r, Wr_z, Wr_h, P, 1536);

    // 3) bf16-pack transposed U
    transpose_pack_u<<<dim3(32, 9), blk, 0, stream>>>(
        Usr_r, Usr_z, Usr_h, Ur_r, Ur_z, Ur_h, Usr2r_r, Usr2r_z, Usr2r_h, UTb);

    // 4) schedule + group table + zeroed flags + ticket
    build_schedule<<<dim3(1), blk, 0, stream>>>(parents, sched, level_off,
                                                gstart, gend, ngrp, ready,
                                                ticket);

    // 5) dataflow scan, dynamic ticket dispatch (cooperative launch
    //    guarantees co-residency for flag polling; no grid.sync used)
    void* args[] = {(void*)&P, (void*)&UTb, (void*)&parents, (void*)&sched,
                    (void*)&gstart, (void*)&gend, (void*)&ngrp, (void*)&ready,
                    (void*)&ticket, (void*)&Ssh, (void*)&Sru};
    (void)hipLaunchCooperativeKernel((const void*)tree_scan_df,
                                     dim3(GRID_WGS), blk, args, 0, stream);

    // 6) epilogue
    epilogue_k<<<dim3(B_TREES), blk, 0, stream>>>(Sru, is_leaf, Vr, br, out);
}